// Round 24
// baseline (81.802 us; speedup 1.0000x reference)
//
#include <hip/hip_runtime.h>

typedef __attribute__((ext_vector_type(8))) short bf16x8;
typedef __attribute__((ext_vector_type(4))) float f32x4;

#define HID 64
#define IN_DIM 128
// binC (float values)
#define RANGE_BITS 14
#define RANGE (1 << RANGE_BITS)   // 16384 nodes per 64 KB float bucket
#define NB 7
#define MCH 36
#define SCAN_TPB 512
// binA (packed u16 counters)
#define RB2 15
#define RANGE2 (1 << RB2)         // 32768 nodes per 64 KB u16 bucket
#define NB2 4
#define MCH2 64
// dense
#define DNODES 64
#define LDSXP 136                 // bf16 row stride: 128 + 8 pad (16 B) -> b128 reads at floor

__device__ __forceinline__ unsigned short f2bf(float f) {   // RTN f32->bf16
    unsigned u = __builtin_bit_cast(unsigned, f);
    return (unsigned short)((u + 0x7FFFu + ((u >> 16) & 1u)) >> 16);
}

// ---------------- prep: Wt[j][k] = bf16(W_in[k][j])  (transposed, 16 KB) ----------------
__global__ __launch_bounds__(256) void k_prep(const float* __restrict__ W_in,
                                              unsigned short* __restrict__ Wt) {
    int i = blockIdx.x * 256 + threadIdx.x;   // 0..8191
    if (i < IN_DIM * HID) {
        int j = i >> 7, k = i & 127;
        Wt[i] = f2bf(W_in[k * HID + j]);
    }
}

// ---------------- dense: MFMA bf16 GEMM tile + fused deg-reduce ----------------
// Block = 64 nodes, 4 waves; wave w computes rows [16w,16w+16) x all 64 channels via
// 16x mfma_f32_16x16x32_bf16 (A from LDS bf16 x-tile, B from L2-hot Wt in regs).
// Epilogue: z = relu(h + b_in) . w_eff per row (shfl reduce), then r23's fused
// deg-unpack -> dinv, zs.
__global__ __launch_bounds__(256) void k_dense(const float* __restrict__ x,
                                               const unsigned short* __restrict__ Wt,
                                               const float* __restrict__ b_in,
                                               const float* __restrict__ W_g,
                                               const float* __restrict__ W_out,
                                               const unsigned* __restrict__ partA,
                                               float* __restrict__ dinv,
                                               float* __restrict__ zs,
                                               int N) {
    __shared__ float weff_l[HID];
    __shared__ float bl[HID];
    __shared__ unsigned short ldsX[DNODES * LDSXP];   // 17.4 KB bf16 x-tile
    __shared__ float zp[DNODES];

    const int t = threadIdx.x;
    const int row0 = blockIdx.x * DNODES;

    // ---- issue x loads: 8 float4/thread (whole 64x128 tile), all in flight ----
    float4 rg[8];
    const int lrow = t >> 3;              // 0..31
    const int lcol = (t & 7) * 4;         // 0,4,...,28
    {
        int gr0 = row0 + lrow;        if (gr0 >= N) gr0 = N - 1;
        int gr1 = row0 + 32 + lrow;   if (gr1 >= N) gr1 = N - 1;
        const float* p0 = x + (size_t)gr0 * IN_DIM + lcol;
        const float* p1 = x + (size_t)gr1 * IN_DIM + lcol;
#pragma unroll
        for (int c = 0; c < 4; ++c) {
            rg[c * 2 + 0] = *(const float4*)(p0 + c * 32);
            rg[c * 2 + 1] = *(const float4*)(p1 + c * 32);
        }
    }

    // ---- weff = W_g @ W_out + bias stage (overlaps x-load latency) ----
    {
        const float* wg = W_g + (t >> 2) * HID + (t & 3) * 16;
        const float* wo = W_out + (t & 3) * 16;
        float s = 0.0f;
#pragma unroll
        for (int p = 0; p < 16; ++p) s = fmaf(wg[p], wo[p], s);
        s += __shfl_xor(s, 1, 64);
        s += __shfl_xor(s, 2, 64);
        if ((t & 3) == 0) weff_l[t >> 2] = s;
        if (t < HID) bl[t] = b_in[t];
    }

    const int w    = __builtin_amdgcn_readfirstlane(t >> 6);  // wave id (SGPR)
    const int lane = t & 63;

    // ---- B fragments: col = nf*16 + (lane&15), k = kk*32 + (lane>>4)*8 (16B each) ----
    bf16x8 bfr[4][4];
    {
        const int col = lane & 15;
        const int ko  = (lane >> 4) * 8;
#pragma unroll
        for (int nf = 0; nf < 4; ++nf)
#pragma unroll
            for (int kk = 0; kk < 4; ++kk)
                bfr[nf][kk] = *(const bf16x8*)(Wt + (size_t)(nf * 16 + col) * IN_DIM + kk * 32 + ko);
    }

    // ---- convert + write x tile to LDS (bf16), one barrier ----
#pragma unroll
    for (int c = 0; c < 4; ++c) {
        float4 v0 = rg[c * 2 + 0], v1 = rg[c * 2 + 1];
        ushort4 h0 = { f2bf(v0.x), f2bf(v0.y), f2bf(v0.z), f2bf(v0.w) };
        ushort4 h1 = { f2bf(v1.x), f2bf(v1.y), f2bf(v1.z), f2bf(v1.w) };
        *(ushort4*)&ldsX[lrow * LDSXP + c * 32 + lcol]        = h0;
        *(ushort4*)&ldsX[(32 + lrow) * LDSXP + c * 32 + lcol] = h1;
    }
    __syncthreads();

    // ---- MFMA: 4 k-steps x 4 n-frags ----
    f32x4 acc[4] = {{0,0,0,0},{0,0,0,0},{0,0,0,0},{0,0,0,0}};
    {
        const int arow = w * 16 + (lane & 15);
        const int ko   = (lane >> 4) * 8;
#pragma unroll
        for (int kk = 0; kk < 4; ++kk) {
            bf16x8 af = *(const bf16x8*)&ldsX[arow * LDSXP + kk * 32 + ko];  // ds_read_b128
#pragma unroll
            for (int nf = 0; nf < 4; ++nf)
                acc[nf] = __builtin_amdgcn_mfma_f32_16x16x32_bf16(af, bfr[nf][kk], acc[nf], 0, 0, 0);
        }
    }

    // ---- epilogue: z[row] = sum_col relu(h + b) * weff ----
    {
        float p[4] = {0.f, 0.f, 0.f, 0.f};
#pragma unroll
        for (int nf = 0; nf < 4; ++nf) {
            const int col = nf * 16 + (lane & 15);
            const float bc = bl[col], wc = weff_l[col];
#pragma unroll
            for (int r = 0; r < 4; ++r)
                p[r] = fmaf(fmaxf(acc[nf][r] + bc, 0.0f), wc, p[r]);
        }
#pragma unroll
        for (int r = 0; r < 4; ++r) {
            p[r] += __shfl_xor(p[r], 1, 64);
            p[r] += __shfl_xor(p[r], 2, 64);
            p[r] += __shfl_xor(p[r], 4, 64);
            p[r] += __shfl_xor(p[r], 8, 64);
        }
        if ((lane & 15) == 0) {
#pragma unroll
            for (int r = 0; r < 4; ++r)
                zp[w * 16 + (lane >> 4) * 4 + r] = p[r];   // C row = (lane>>4)*4 + r
        }
    }
    __syncthreads();

    // ---- fused redDeg: wave 0 unpacks deg partials -> dinv, zs ----
    if (t < 64) {
        int n = row0 + t; if (n >= N) n = N - 1;
        float z = zp[t];
        const int r = n >> RB2, idx = n & (RANGE2 - 1);
        const int sh = (idx & 1) << 4;
        const unsigned* base = partA + (size_t)r * (RANGE2 / 2) + (idx >> 1);
        const size_t stride = (size_t)NB2 * (RANGE2 / 2);
        int d = 0;
#pragma unroll 8
        for (int m = 0; m < MCH2; ++m)
            d += (int)((base[m * stride] >> sh) & 0xFFFFu);
        float di = rsqrtf((float)d + 1.0f);
        dinv[n] = di;
        zs[n]   = z * di;
    }
}

// ---------------- pass A: binned degree count, packed u16 (LDS atomics only) ----------------
__global__ __launch_bounds__(SCAN_TPB) void k_binA(const int* __restrict__ dst,
                                                   unsigned* __restrict__ partA,
                                                   int E, int chunkA) {
    __shared__ unsigned cnt[RANGE2 / 2];   // 64 KB, 2 nodes per word
    for (int i = threadIdx.x; i < RANGE2 / 2; i += SCAN_TPB) cnt[i] = 0;
    __syncthreads();

    const int r = blockIdx.x % NB2;
    const int lo = r << RB2;
    const int e0 = (blockIdx.x / NB2) * chunkA;
    const int e1 = min(E, e0 + chunkA);
    for (int e = e0 + (int)threadIdx.x * 4; e + 3 < e1; e += SCAN_TPB * 4) {
        int4 d4 = *(const int4*)(dst + e);
        unsigned v;
        v = (unsigned)(d4.x - lo); if (v < RANGE2) atomicAdd(&cnt[v >> 1], 1u << ((v & 1) << 4));
        v = (unsigned)(d4.y - lo); if (v < RANGE2) atomicAdd(&cnt[v >> 1], 1u << ((v & 1) << 4));
        v = (unsigned)(d4.z - lo); if (v < RANGE2) atomicAdd(&cnt[v >> 1], 1u << ((v & 1) << 4));
        v = (unsigned)(d4.w - lo); if (v < RANGE2) atomicAdd(&cnt[v >> 1], 1u << ((v & 1) << 4));
    }
    __syncthreads();

    unsigned* outp = partA + (size_t)blockIdx.x * (RANGE2 / 2);
    for (int i = threadIdx.x; i < RANGE2 / 2; i += SCAN_TPB) outp[i] = cnt[i];
}

// ---------------- pass C: binned value scatter (LDS float atomics only) ----------------
__global__ __launch_bounds__(SCAN_TPB) void k_binC(const int* __restrict__ eidx,
                                                   const float* __restrict__ zs,
                                                   float* __restrict__ partf,
                                                   int E, int chunk) {
    __shared__ float acc[RANGE];
    for (int i = threadIdx.x; i < RANGE; i += SCAN_TPB) acc[i] = 0.0f;
    __syncthreads();

    const int r = blockIdx.x % NB;
    const int lo = r << RANGE_BITS;
    const int e0 = (blockIdx.x / NB) * chunk;
    const int e1 = min(E, e0 + chunk);
    for (int e = e0 + (int)threadIdx.x * 4; e + 3 < e1; e += SCAN_TPB * 4) {
        int4 s4 = *(const int4*)(eidx + e);        // src
        int4 d4 = *(const int4*)(eidx + E + e);    // dst
        unsigned v;
        v = (unsigned)(d4.x - lo); if (v < RANGE) atomicAdd(&acc[v], zs[s4.x]);
        v = (unsigned)(d4.y - lo); if (v < RANGE) atomicAdd(&acc[v], zs[s4.y]);
        v = (unsigned)(d4.z - lo); if (v < RANGE) atomicAdd(&acc[v], zs[s4.z]);
        v = (unsigned)(d4.w - lo); if (v < RANGE) atomicAdd(&acc[v], zs[s4.w]);
    }
    __syncthreads();

    float* outp = partf + (size_t)blockIdx.x * RANGE;
    for (int i = threadIdx.x; i < RANGE; i += SCAN_TPB) outp[i] = acc[i];
}

// ------- final: out = dinv * (sum partials + zs[self]) + (b_g.W_out + b_out) -------
__global__ __launch_bounds__(256) void k_redFinal(const float* __restrict__ partf,
                                                  const float* __restrict__ dinv,
                                                  const float* __restrict__ zs,
                                                  const float* __restrict__ b_g,
                                                  const float* __restrict__ W_out,
                                                  const float* __restrict__ b_out,
                                                  float* __restrict__ out, int N) {
    const int lane = threadIdx.x & 63;
    float c = b_g[lane] * W_out[lane];
#pragma unroll
    for (int off = 32; off > 0; off >>= 1)
        c += __shfl_xor(c, off, 64);
    c += b_out[0];

    int i = blockIdx.x * blockDim.x + threadIdx.x;
    if (i >= N) return;
    const int r = i >> RANGE_BITS, idx = i & (RANGE - 1);
    float a = zs[i];   // self-loop
#pragma unroll 4
    for (int m = 0; m < MCH; ++m)
        a += partf[((size_t)m * NB + r) * RANGE + idx];
    out[i] = fmaf(dinv[i], a, c);
}

// ---------------- launch ----------------

extern "C" void kernel_launch(void* const* d_in, const int* in_sizes, int n_in,
                              void* d_out, int out_size, void* d_ws, size_t ws_size,
                              hipStream_t stream) {
    const float* x     = (const float*)d_in[0];
    const int*   eidx  = (const int*)d_in[1];
    const float* W_in  = (const float*)d_in[2];
    const float* b_in  = (const float*)d_in[3];
    const float* W_g   = (const float*)d_in[4];
    const float* b_g   = (const float*)d_in[5];
    const float* W_out = (const float*)d_in[6];
    const float* b_out = (const float*)d_in[7];
    float* out = (float*)d_out;

    const int N = in_sizes[0] / IN_DIM;   // 100000
    const int E = in_sizes[1] / 2;        // 1600000

    // chunks: multiples of 4
    const int chunk  = (((E + MCH  - 1) / MCH ) + 3) & ~3;
    const int chunkA = (((E + MCH2 - 1) / MCH2) + 3) & ~3;

    // ws layout: region0 = max(partf, partA) | dinv[N] | zs[N] | Wt[8192 bf16]
    const size_t partElems0 = (size_t)NB * MCH * RANGE;              // binC floats
    const size_t partElemsA = (size_t)NB2 * MCH2 * (RANGE2 / 2);     // binA u32 words
    const size_t partElems = partElems0 > partElemsA ? partElems0 : partElemsA;
    unsigned* partA = (unsigned*)d_ws;    // consumed by k_dense before binC overwrites
    float*    partf = (float*)d_ws;
    float*    dinv  = (float*)d_ws + partElems;
    float*    zs    = dinv + N;
    unsigned short* Wt = (unsigned short*)(zs + N);

    const int nG = (N + DNODES - 1) / DNODES;   // 1563 dense blocks
    k_prep<<<(IN_DIM * HID + 255) / 256, 256, 0, stream>>>(W_in, Wt);
    k_binA<<<NB2 * MCH2, SCAN_TPB, 0, stream>>>(eidx + E, partA, E, chunkA);
    k_dense<<<nG, 256, 0, stream>>>(x, Wt, b_in, W_g, W_out, partA, dinv, zs, N);
    k_binC<<<NB * MCH, SCAN_TPB, 0, stream>>>(eidx, zs, partf, E, chunk);
    k_redFinal<<<(N + 255) / 256, 256, 0, stream>>>(partf, dinv, zs, b_g, W_out, b_out, out, N);
}

// Round 25
// 79.473 us; speedup vs baseline: 1.0293x; 1.0293x over previous
//
#include <hip/hip_runtime.h>

typedef __attribute__((ext_vector_type(8))) short bf16x8;
typedef __attribute__((ext_vector_type(4))) float f32x4;

#define HID 64
#define IN_DIM 128
// binC (float values)
#define RANGE_BITS 14
#define RANGE (1 << RANGE_BITS)   // 16384 nodes per 64 KB float bucket
#define NB 7
#define MCH 36
#define SCAN_TPB 512
// binA (packed u16 counters)
#define RB2 15
#define RANGE2 (1 << RB2)         // 32768 nodes per 64 KB u16 bucket
#define NB2 4
#define MCH2 64
#define PREP_BLOCKS 16            // prep blocks appended to binA grid
// dense
#define DNODES 64

__device__ __forceinline__ unsigned short f2bf(float f) {   // RTN f32->bf16
    unsigned u = __builtin_bit_cast(unsigned, f);
    return (unsigned short)((u + 0x7FFFu + ((u >> 16) & 1u)) >> 16);
}

// ------- binA (+prep): binned degree count, packed u16; last 16 blocks build Wt -------
__global__ __launch_bounds__(SCAN_TPB) void k_binA(const int* __restrict__ dst,
                                                   unsigned* __restrict__ partA,
                                                   const float* __restrict__ W_in,
                                                   unsigned short* __restrict__ Wt,
                                                   int E, int chunkA) {
    if ((int)blockIdx.x >= NB2 * MCH2) {
        // prep: Wt[j][k] = bf16(W_in[k][j])
        int i = (blockIdx.x - NB2 * MCH2) * SCAN_TPB + threadIdx.x;
        if (i < IN_DIM * HID) Wt[i] = f2bf(W_in[(i & 127) * HID + (i >> 7)]);
        return;
    }

    __shared__ unsigned cnt[RANGE2 / 2];   // 64 KB, 2 nodes per word
    for (int i = threadIdx.x; i < RANGE2 / 2; i += SCAN_TPB) cnt[i] = 0;
    __syncthreads();

    const int r = blockIdx.x % NB2;
    const int lo = r << RB2;
    const int e0 = (blockIdx.x / NB2) * chunkA;
    const int e1 = min(E, e0 + chunkA);
    for (int e = e0 + (int)threadIdx.x * 4; e + 3 < e1; e += SCAN_TPB * 4) {
        int4 d4 = *(const int4*)(dst + e);
        unsigned v;
        v = (unsigned)(d4.x - lo); if (v < RANGE2) atomicAdd(&cnt[v >> 1], 1u << ((v & 1) << 4));
        v = (unsigned)(d4.y - lo); if (v < RANGE2) atomicAdd(&cnt[v >> 1], 1u << ((v & 1) << 4));
        v = (unsigned)(d4.z - lo); if (v < RANGE2) atomicAdd(&cnt[v >> 1], 1u << ((v & 1) << 4));
        v = (unsigned)(d4.w - lo); if (v < RANGE2) atomicAdd(&cnt[v >> 1], 1u << ((v & 1) << 4));
    }
    __syncthreads();

    unsigned* outp = partA + (size_t)blockIdx.x * (RANGE2 / 2);
    for (int i = threadIdx.x; i < RANGE2 / 2; i += SCAN_TPB) outp[i] = cnt[i];
}

// ---------------- dense: MFMA, A-frags direct from global (no x LDS tile) ----------------
// Block = 64 nodes, 4 waves; wave w: rows [16w,16w+16). A-frag: lane reads 2 float4 of
// x[row0+w*16+(lane&15)] at col (lane>>4)*8 + kk*32, converts f32->bf16 in regs.
// B from L2-hot Wt. Epilogue z = relu(h+b).w_eff (shfl reduce). Tail: deg-unpack
// parallelized over all 256 threads (4 m-quarters/node).
__global__ __launch_bounds__(256) void k_dense(const float* __restrict__ x,
                                               const unsigned short* __restrict__ Wt,
                                               const float* __restrict__ b_in,
                                               const float* __restrict__ W_g,
                                               const float* __restrict__ W_out,
                                               const unsigned* __restrict__ partA,
                                               float* __restrict__ dinv,
                                               float* __restrict__ zs,
                                               int N) {
    __shared__ float weff_l[HID];
    __shared__ float bl[HID];
    __shared__ float zp[DNODES];
    __shared__ int   tailp[4][DNODES];

    const int t = threadIdx.x;
    const int row0 = blockIdx.x * DNODES;

    // ---- weff = W_g @ W_out + bias stage ----
    {
        const float* wg = W_g + (t >> 2) * HID + (t & 3) * 16;
        const float* wo = W_out + (t & 3) * 16;
        float s = 0.0f;
#pragma unroll
        for (int p = 0; p < 16; ++p) s = fmaf(wg[p], wo[p], s);
        s += __shfl_xor(s, 1, 64);
        s += __shfl_xor(s, 2, 64);
        if ((t & 3) == 0) weff_l[t >> 2] = s;
        if (t < HID) bl[t] = b_in[t];
    }

    const int w    = __builtin_amdgcn_readfirstlane(t >> 6);  // wave id (SGPR)
    const int lane = t & 63;

    // ---- B fragments: col = nf*16 + (lane&15), k = kk*32 + (lane>>4)*8 ----
    bf16x8 bfr[4][4];
    {
        const int col = lane & 15;
        const int ko  = (lane >> 4) * 8;
#pragma unroll
        for (int nf = 0; nf < 4; ++nf)
#pragma unroll
            for (int kk = 0; kk < 4; ++kk)
                bfr[nf][kk] = *(const bf16x8*)(Wt + (size_t)(nf * 16 + col) * IN_DIM + kk * 32 + ko);
    }

    // ---- A direct from global + MFMA ----
    f32x4 acc[4] = {{0,0,0,0},{0,0,0,0},{0,0,0,0},{0,0,0,0}};
    {
        int grow = row0 + w * 16 + (lane & 15);
        if (grow >= N) grow = N - 1;
        const float* xr = x + (size_t)grow * IN_DIM + (lane >> 4) * 8;
#pragma unroll
        for (int kk = 0; kk < 4; ++kk) {
            float4 a0 = *(const float4*)(xr + kk * 32);
            float4 a1 = *(const float4*)(xr + kk * 32 + 4);
            bf16x8 af;
            af[0] = (short)f2bf(a0.x); af[1] = (short)f2bf(a0.y);
            af[2] = (short)f2bf(a0.z); af[3] = (short)f2bf(a0.w);
            af[4] = (short)f2bf(a1.x); af[5] = (short)f2bf(a1.y);
            af[6] = (short)f2bf(a1.z); af[7] = (short)f2bf(a1.w);
#pragma unroll
            for (int nf = 0; nf < 4; ++nf)
                acc[nf] = __builtin_amdgcn_mfma_f32_16x16x32_bf16(af, bfr[nf][kk], acc[nf], 0, 0, 0);
        }
    }
    __syncthreads();   // weff_l/bl ready (written at kernel start)

    // ---- epilogue: z[row] = sum_col relu(h + b) * weff ----
    {
        float p[4] = {0.f, 0.f, 0.f, 0.f};
#pragma unroll
        for (int nf = 0; nf < 4; ++nf) {
            const int col = nf * 16 + (lane & 15);
            const float bc = bl[col], wc = weff_l[col];
#pragma unroll
            for (int r = 0; r < 4; ++r)
                p[r] = fmaf(fmaxf(acc[nf][r] + bc, 0.0f), wc, p[r]);
        }
#pragma unroll
        for (int r = 0; r < 4; ++r) {
            p[r] += __shfl_xor(p[r], 1, 64);
            p[r] += __shfl_xor(p[r], 2, 64);
            p[r] += __shfl_xor(p[r], 4, 64);
            p[r] += __shfl_xor(p[r], 8, 64);
        }
        if ((lane & 15) == 0) {
#pragma unroll
            for (int r = 0; r < 4; ++r)
                zp[w * 16 + (lane >> 4) * 4 + r] = p[r];   // C row = (lane>>4)*4 + r
        }
    }

    // ---- tail: deg-unpack parallelized 4x (thread = node x m-quarter) ----
    {
        const int tn = t & 63;
        const int tq = t >> 6;
        int n = row0 + tn; if (n >= N) n = N - 1;
        const int r = n >> RB2, idx = n & (RANGE2 - 1);
        const int sh = (idx & 1) << 4;
        const unsigned* base = partA + (size_t)r * (RANGE2 / 2) + (idx >> 1);
        const size_t stride = (size_t)NB2 * (RANGE2 / 2);
        int d = 0;
#pragma unroll
        for (int j = 0; j < 16; ++j)
            d += (int)((base[(size_t)(tq * 16 + j) * stride] >> sh) & 0xFFFFu);
        tailp[tq][tn] = d;
    }
    __syncthreads();   // zp + tailp ready

    if (t < 64) {
        int n = row0 + t; if (n >= N) n = N - 1;
        int d = tailp[0][t] + tailp[1][t] + tailp[2][t] + tailp[3][t];
        float di = rsqrtf((float)d + 1.0f);
        dinv[n] = di;
        zs[n]   = zp[t] * di;
    }
}

// ---------------- pass C: binned value scatter (LDS float atomics only) ----------------
__global__ __launch_bounds__(SCAN_TPB) void k_binC(const int* __restrict__ eidx,
                                                   const float* __restrict__ zs,
                                                   float* __restrict__ partf,
                                                   int E, int chunk) {
    __shared__ float acc[RANGE];
    for (int i = threadIdx.x; i < RANGE; i += SCAN_TPB) acc[i] = 0.0f;
    __syncthreads();

    const int r = blockIdx.x % NB;
    const int lo = r << RANGE_BITS;
    const int e0 = (blockIdx.x / NB) * chunk;
    const int e1 = min(E, e0 + chunk);
    for (int e = e0 + (int)threadIdx.x * 4; e + 3 < e1; e += SCAN_TPB * 4) {
        int4 s4 = *(const int4*)(eidx + e);        // src
        int4 d4 = *(const int4*)(eidx + E + e);    // dst
        unsigned v;
        v = (unsigned)(d4.x - lo); if (v < RANGE) atomicAdd(&acc[v], zs[s4.x]);
        v = (unsigned)(d4.y - lo); if (v < RANGE) atomicAdd(&acc[v], zs[s4.y]);
        v = (unsigned)(d4.z - lo); if (v < RANGE) atomicAdd(&acc[v], zs[s4.z]);
        v = (unsigned)(d4.w - lo); if (v < RANGE) atomicAdd(&acc[v], zs[s4.w]);
    }
    __syncthreads();

    float* outp = partf + (size_t)blockIdx.x * RANGE;
    for (int i = threadIdx.x; i < RANGE; i += SCAN_TPB) outp[i] = acc[i];
}

// ------- final: out = dinv * (sum partials + zs[self]) + (b_g.W_out + b_out) -------
__global__ __launch_bounds__(256) void k_redFinal(const float* __restrict__ partf,
                                                  const float* __restrict__ dinv,
                                                  const float* __restrict__ zs,
                                                  const float* __restrict__ b_g,
                                                  const float* __restrict__ W_out,
                                                  const float* __restrict__ b_out,
                                                  float* __restrict__ out, int N) {
    const int lane = threadIdx.x & 63;
    float c = b_g[lane] * W_out[lane];
#pragma unroll
    for (int off = 32; off > 0; off >>= 1)
        c += __shfl_xor(c, off, 64);
    c += b_out[0];

    int i = blockIdx.x * blockDim.x + threadIdx.x;
    if (i >= N) return;
    const int r = i >> RANGE_BITS, idx = i & (RANGE - 1);
    float a = zs[i];   // self-loop
#pragma unroll 4
    for (int m = 0; m < MCH; ++m)
        a += partf[((size_t)m * NB + r) * RANGE + idx];
    out[i] = fmaf(dinv[i], a, c);
}

// ---------------- launch ----------------

extern "C" void kernel_launch(void* const* d_in, const int* in_sizes, int n_in,
                              void* d_out, int out_size, void* d_ws, size_t ws_size,
                              hipStream_t stream) {
    const float* x     = (const float*)d_in[0];
    const int*   eidx  = (const int*)d_in[1];
    const float* W_in  = (const float*)d_in[2];
    const float* b_in  = (const float*)d_in[3];
    const float* W_g   = (const float*)d_in[4];
    const float* b_g   = (const float*)d_in[5];
    const float* W_out = (const float*)d_in[6];
    const float* b_out = (const float*)d_in[7];
    float* out = (float*)d_out;

    const int N = in_sizes[0] / IN_DIM;   // 100000
    const int E = in_sizes[1] / 2;        // 1600000

    // chunks: multiples of 4
    const int chunk  = (((E + MCH  - 1) / MCH ) + 3) & ~3;
    const int chunkA = (((E + MCH2 - 1) / MCH2) + 3) & ~3;

    // ws layout: region0 = max(partf, partA) | dinv[N] | zs[N] | Wt[8192 bf16]
    const size_t partElems0 = (size_t)NB * MCH * RANGE;              // binC floats
    const size_t partElemsA = (size_t)NB2 * MCH2 * (RANGE2 / 2);     // binA u32 words
    const size_t partElems = partElems0 > partElemsA ? partElems0 : partElemsA;
    unsigned* partA = (unsigned*)d_ws;    // consumed by k_dense before binC overwrites
    float*    partf = (float*)d_ws;
    float*    dinv  = (float*)d_ws + partElems;
    float*    zs    = dinv + N;
    unsigned short* Wt = (unsigned short*)(zs + N);

    const int nG = (N + DNODES - 1) / DNODES;   // 1563 dense blocks
    k_binA<<<NB2 * MCH2 + PREP_BLOCKS, SCAN_TPB, 0, stream>>>(eidx + E, partA, W_in, Wt, E, chunkA);
    k_dense<<<nG, 256, 0, stream>>>(x, Wt, b_in, W_g, W_out, partA, dinv, zs, N);
    k_binC<<<NB * MCH, SCAN_TPB, 0, stream>>>(eidx, zs, partf, E, chunk);
    k_redFinal<<<(N + 255) / 256, 256, 0, stream>>>(partf, dinv, zs, b_g, W_out, b_out, out, N);
}